// Round 13
// baseline (73.968 us; speedup 1.0000x reference)
//
#include <hip/hip_runtime.h>
#include <stdint.h>

#define BB 8
#define CC 19
#define HH 512
#define WW 1024
#define KK 15
#define RR 7
#define TH 8
#define WHALF 512
#define NROWS (TH + 2*RR)          // 22 staged rows
#define P_DW 18                    // 17 data dw (cols w0-16 .. w0+527) + 1 tail pad
#define NK 136                     // int4 loads per staged row (544 cols)
#define HW (HH*WW)
#define NPIX (BB*HH*WW)            // 4194304
#define NBLK (BB*(HH/TH)*2)        // 1024
#define PXB (TH*WHALF)             // 4096 pixels per block

__global__ __launch_bounds__(256) void wce_main(const float* __restrict__ in,
                                                const int* __restrict__ tg,
                                                float* __restrict__ part) {
  __shared__ uint32_t P[CC][NROWS][P_DW];     // 30096 B bit-planes
  __shared__ uint32_t Cc[TH][WHALF/4];        // 4096 B packed center classes
  __shared__ float    wbuf[PXB];              // 16384 B per-pixel weights
  __shared__ uint16_t sidx[PXB];              // 8192 B class-sorted pixel idx
  __shared__ uint32_t hist[CC][8];            // 608 B split histogram
  __shared__ uint32_t off[CC];                // 76 B running offsets
  __shared__ float wpart[4];
  const int tid = threadIdx.x;
  const int blk = blockIdx.x;
  const int bb  = blk >> 7;                   // 128 (h,half)-blocks per batch
  const int rem = blk & 127;
  const int h0  = (rem >> 1) * TH;
  const int w0  = (rem & 1) * WHALF;

  // ---- zero planes + histogram ----
  uint32_t* pflat = &P[0][0][0];
  #pragma unroll 4
  for (int i = tid; i < CC*NROWS*P_DW; i += 256) pflat[i] = 0;
  if (tid < CC*8) (&hist[0][0])[tid] = 0;
  __syncthreads();

  // ---- build bit-planes (unwritten cols stay 0 = box-filter zero pad) ----
  for (int idx = tid; idx < NROWS*NK; idx += 256) {
    const int r = idx / NK;                   // 0..21
    const int k = idx - r*NK;                 // 0..135
    const int h = h0 - RR + r;
    const int wg = w0 - 16 + 4*k;             // global col of this int4
    if (h >= 0 && h < HH && wg >= 0 && wg < WW) {
      const int4 t4 = *reinterpret_cast<const int4*>(&tg[(bb*HH + h)*WW + wg]);
      const int rc = r - RR;
      if (rc >= 0 && rc < TH && k >= 4 && k < 132)
        Cc[rc][k-4] = (uint32_t)(t4.x & 0xff)        | ((uint32_t)(t4.y & 0xff) << 8)
                    | ((uint32_t)(t4.z & 0xff) << 16) | ((uint32_t)(t4.w & 0xff) << 24);
      const int dw = k >> 3;                  // bit col = 4k
      const int b  = (4*k) & 31;
      atomicOr(&P[t4.x][r][dw], 1u << (b + 0));
      atomicOr(&P[t4.y][r][dw], 1u << (b + 1));
      atomicOr(&P[t4.z][r][dw], 1u << (b + 2));
      atomicOr(&P[t4.w][r][dw], 1u << (b + 3));
    }
  }
  __syncthreads();

  const int g  = tid & 127;                   // col group: cols w0+4g..4g+3
  const int sb = (tid >> 7) << 2;             // step range: [sb, sb+4)

  // ---- phase B: popcount -> weights in LDS; class histogram ----
  #pragma unroll
  for (int so = 0; so < 4; ++so) {
    const int s = sb + so;
    const uint32_t c4 = Cc[s][g];
    #pragma unroll
    for (int i = 0; i < 4; ++i) {
      const int c  = (int)((c4 >> (8*i)) & 0xff);
      const int lb = 4*g + i + 9;             // local bit col of window start
      const int q  = lb >> 5;
      const int sh = lb & 31;
      const uint32_t* pr = &P[c][s][q];
      int cn = 0;
      #pragma unroll
      for (int wr = 0; wr < KK; ++wr) {
        const uint32_t lo = pr[0], hi = pr[1];
        cn += __popc(__builtin_amdgcn_alignbit(hi, lo, sh) & 0x7fffu);
        pr += P_DW;
      }
      wbuf[(s << 9) + 4*g + i] = 225.0f / (float)cn;   // cn >= 1
      atomicAdd(&hist[c][tid & 7], 1u);
    }
  }
  __syncthreads();

  // ---- phase C: totals + exclusive prefix over 19 classes ----
  if (tid < CC) {
    uint32_t t = 0;
    #pragma unroll
    for (int k = 0; k < 8; ++k) t += hist[tid][k];
    hist[tid][0] = t;
  }
  __syncthreads();
  if (tid == 0) {
    uint32_t run = 0;
    for (int c = 0; c < CC; ++c) { off[c] = run; run += hist[c][0]; }
  }
  __syncthreads();

  // ---- phase D: scatter pixel indices in class-major order ----
  #pragma unroll
  for (int so = 0; so < 4; ++so) {
    const int s = sb + so;
    const uint32_t c4 = Cc[s][g];
    #pragma unroll
    for (int i = 0; i < 4; ++i) {
      const int c = (int)((c4 >> (8*i)) & 0xff);
      const uint32_t pos = atomicAdd(&off[c], 1u);
      sidx[pos] = (uint16_t)((s << 9) + 4*g + i);
    }
  }
  __syncthreads();

  // ---- phase E: class-clustered gather + accumulate ----
  const int gbase = bb*CC*HW + h0*WW + w0;
  float acc = 0.0f;
  #pragma unroll 4
  for (int i = 0; i < PXB/256; ++i) {
    const int j  = (i << 8) + tid;            // lanes take consecutive sorted slots
    const int p  = (int)sidx[j];
    const int s  = p >> 9, wl = p & 511;
    const uint32_t cw = Cc[s][wl >> 2];
    const int c  = (int)((cw >> ((wl & 3)*8)) & 0xff);
    acc += wbuf[p] * in[gbase + s*WW + wl + c*HW];
  }

  // ---- block reduction ----
  #pragma unroll
  for (int o = 32; o > 0; o >>= 1) acc += __shfl_down(acc, o, 64);
  const int lane = tid & 63, wv = tid >> 6;
  if (lane == 0) wpart[wv] = acc;
  __syncthreads();
  if (tid == 0) part[blk] = wpart[0] + wpart[1] + wpart[2] + wpart[3];
}

__global__ __launch_bounds__(256) void wce_reduce(const float* __restrict__ part,
                                                  float* __restrict__ out, int n) {
  __shared__ float wpart[4];
  float a = 0.0f;
  for (int i = threadIdx.x; i < n; i += 256) a += part[i];
  #pragma unroll
  for (int o = 32; o > 0; o >>= 1) a += __shfl_down(a, o, 64);
  const int lane = threadIdx.x & 63, wv = threadIdx.x >> 6;
  if (lane == 0) wpart[wv] = a;
  __syncthreads();
  if (threadIdx.x == 0) {
    const float tot = wpart[0] + wpart[1] + wpart[2] + wpart[3];
    out[0] = -tot / (float)NPIX;
  }
}

extern "C" void kernel_launch(void* const* d_in, const int* in_sizes, int n_in,
                              void* d_out, int out_size, void* d_ws, size_t ws_size,
                              hipStream_t stream) {
  const float* in = (const float*)d_in[0];
  const int*   tg = (const int*)d_in[1];
  float* out  = (float*)d_out;
  float* part = (float*)d_ws;

  wce_main<<<NBLK, 256, 0, stream>>>(in, tg, part);
  wce_reduce<<<1, 256, 0, stream>>>(part, out, NBLK);
}

// Round 14
// 52.997 us; speedup vs baseline: 1.3957x; 1.3957x over previous
//
#include <hip/hip_runtime.h>
#include <stdint.h>

#define BB 8
#define CC 19
#define HH 512
#define WW 1024
#define KK 15
#define RR 7
#define TH 8
#define NROWS (TH + 2*RR)          // 22 staged rows
#define P_DW 34                    // 1 pad dw + 32 data dw + 1 pad dw
#define HW (HH*WW)
#define NPIX (BB*HH*WW)            // 4194304
#define NBLK (BB*(HH/TH))          // 512

__global__ __launch_bounds__(256) void wce_main(const float* __restrict__ in,
                                                const int* __restrict__ tg,
                                                float* __restrict__ part) {
  // per-class bit-planes of the staged 22-row strip: bit = (class at that pixel)
  __shared__ uint32_t P[CC][NROWS][P_DW];     // 56848 B
  __shared__ uint32_t Cc[TH][256];            // packed center classes, 8192 B
  __shared__ float wpart[4];
  const int tid = threadIdx.x;
  const int blk = blockIdx.x;
  const int bb  = blk >> 6;           // 64 h-blocks per batch (512/TH)
  const int h0  = (blk & 63) * TH;

  // ---- zero the bit-planes ----
  uint32_t* pflat = &P[0][0][0];
  #pragma unroll 4
  for (int i = tid; i < CC*NROWS*P_DW; i += 256) pflat[i] = 0;
  __syncthreads();

  // ---- build bit-planes (zero-padded borders = reference's zero box-filter pad) ----
  for (int idx = tid; idx < NROWS*256; idx += 256) {
    const int r = idx >> 8, d = idx & 255;
    const int h = h0 - RR + r;
    if (h >= 0 && h < HH) {
      const int4 t4 = *reinterpret_cast<const int4*>(&tg[(bb*HH + h)*WW + d*4]);
      const int rc = r - RR;
      if (rc >= 0 && rc < TH)
        Cc[rc][d] = (uint32_t)(t4.x & 0xff)        | ((uint32_t)(t4.y & 0xff) << 8)
                  | ((uint32_t)(t4.z & 0xff) << 16) | ((uint32_t)(t4.w & 0xff) << 24);
      const int col = d * 4;              // cols col..col+3 live in the same dword
      const int dw  = 1 + (col >> 5);
      const int b   = col & 31;
      atomicOr(&P[t4.x][r][dw], 1u << (b + 0));
      atomicOr(&P[t4.y][r][dw], 1u << (b + 1));
      atomicOr(&P[t4.z][r][dw], 1u << (b + 2));
      atomicOr(&P[t4.w][r][dw], 1u << (b + 3));
    }
  }
  __syncthreads();

  const int g = tid;                  // this thread's 4-px group: w = 4g..4g+3
  float acc = 0.0f;

  // gather step s_ into named regs (4 loads issued back-to-back)
  #define GATHER(s_, c4_, v0_, v1_, v2_, v3_) do {                              \
    (c4_) = Cc[(s_)][g];                                                        \
    const int b_ = bb*CC*HW + (h0 + (s_))*WW + 4*g;                             \
    (v0_) = in[b_ + (int)( (c4_)        & 0xff)*HW + 0];                        \
    (v1_) = in[b_ + (int)(((c4_) >> 8)  & 0xff)*HW + 1];                        \
    (v2_) = in[b_ + (int)(((c4_) >> 16) & 0xff)*HW + 2];                        \
    (v3_) = in[b_ + (int)(((c4_) >> 24) & 0xff)*HW + 3];                        \
  } while (0)

  // bit-plane popcount window for step s_ consuming named regs
  #define WINDOW(s_, c4_, v0_, v1_, v2_, v3_) do {                              \
    float xv[4] = { (v0_), (v1_), (v2_), (v3_) };                               \
    _Pragma("unroll")                                                           \
    for (int i = 0; i < 4; ++i) {                                               \
      const int c  = (int)(((c4_) >> (8*i)) & 0xff);                            \
      const int lb = 4*g + i - 7;                                               \
      const int q  = (lb >> 5) + 1;                                             \
      const int sh = lb & 31;                                                   \
      const uint32_t* pr = &P[c][(s_)][q];                                      \
      int cn = 0;                                                               \
      _Pragma("unroll")                                                         \
      for (int wr = 0; wr < KK; ++wr) {                                         \
        const uint32_t lo = pr[0], hi = pr[1];                                  \
        cn += __popc(__builtin_amdgcn_alignbit(hi, lo, sh) & 0x7fffu);          \
        pr += P_DW;                                                             \
      }                                                                         \
      acc += xv[i] * (225.0f / (float)cn);                                      \
    }                                                                           \
  } while (0)

  // ---- depth-2 pipeline: 8 loads in flight, named registers (no spills) ----
  uint32_t c4a, c4b;
  float a0, a1, a2, a3, b0, b1, b2, b3;
  GATHER(0, c4a, a0, a1, a2, a3);

  #pragma unroll 1
  for (int s = 0; s < TH; s += 2) {
    GATHER(s + 1, c4b, b0, b1, b2, b3);        // next-step loads in flight
    WINDOW(s, c4a, a0, a1, a2, a3);            // compute under them
    const int s2 = (s + 2 < TH) ? s + 2 : s;   // tail: harmless redundant reload
    GATHER(s2, c4a, a0, a1, a2, a3);
    WINDOW(s + 1, c4b, b0, b1, b2, b3);
  }
  #undef GATHER
  #undef WINDOW

  // ---- block reduction ----
  #pragma unroll
  for (int off = 32; off > 0; off >>= 1) acc += __shfl_down(acc, off, 64);
  const int lane = tid & 63, wv = tid >> 6;
  if (lane == 0) wpart[wv] = acc;
  __syncthreads();
  if (tid == 0) part[blk] = wpart[0] + wpart[1] + wpart[2] + wpart[3];
}

__global__ __launch_bounds__(256) void wce_reduce(const float* __restrict__ part,
                                                  float* __restrict__ out, int n) {
  __shared__ float wpart[4];
  float a = 0.0f;
  for (int i = threadIdx.x; i < n; i += 256) a += part[i];
  #pragma unroll
  for (int off = 32; off > 0; off >>= 1) a += __shfl_down(a, off, 64);
  const int lane = threadIdx.x & 63, wv = threadIdx.x >> 6;
  if (lane == 0) wpart[wv] = a;
  __syncthreads();
  if (threadIdx.x == 0) {
    const float tot = wpart[0] + wpart[1] + wpart[2] + wpart[3];
    out[0] = -tot / (float)NPIX;
  }
}

extern "C" void kernel_launch(void* const* d_in, const int* in_sizes, int n_in,
                              void* d_out, int out_size, void* d_ws, size_t ws_size,
                              hipStream_t stream) {
  const float* in = (const float*)d_in[0];
  const int*   tg = (const int*)d_in[1];
  float* out  = (float*)d_out;
  float* part = (float*)d_ws;

  wce_main<<<NBLK, 256, 0, stream>>>(in, tg, part);
  wce_reduce<<<1, 256, 0, stream>>>(part, out, NBLK);
}